// Round 4
// baseline (458.712 us; speedup 1.0000x reference)
//
#include <hip/hip_runtime.h>

#define BB 512
#define II 1152
#define OO 10
#define DD 16
#define JJ 8
#define OD 160           // OO*DD
#define KK (II*JJ)       // 9216

// s_part config
#define BT 32            // b-tile
#define NBT (BB/BT)      // 16
#define IC 16            // i-chunk
#define NS (II/IC)       // 72

// ---------------- transpose x[b][k] -> xT[k][b] ----------------
__global__ __launch_bounds__(256) void k_transpose(const float* __restrict__ x,
                                                   float* __restrict__ xT) {
  __shared__ float tile[32][33];
  int kb = blockIdx.x;            // 288 tiles of k
  int bb = blockIdx.y;            // 16 tiles of b
  int tx = threadIdx.x & 31, ty = threadIdx.x >> 5;  // 32 x 8
  int k0 = kb * 32, b0 = bb * 32;
#pragma unroll
  for (int r = ty; r < 32; r += 8)
    tile[r][tx] = x[(size_t)(b0 + r) * KK + k0 + tx];
  __syncthreads();
#pragma unroll
  for (int r = ty; r < 32; r += 8)
    xT[(size_t)(k0 + r) * BB + b0 + tx] = tile[tx][r];
}

// ---------------- fill c with uniform 1/1152 (softmax of zeros) ----------------
__global__ __launch_bounds__(256) void k_fill(float* __restrict__ c) {
  c[blockIdx.x * 256 + threadIdx.x] = 1.0f / 1152.0f;
}

// ---------------- b update (from agreep[od][i]) + softmax over i ----------------
__global__ __launch_bounds__(256) void k_bupd_softmax(float* __restrict__ b_ij,
                                                      const float* __restrict__ agreep,
                                                      float* __restrict__ c) {
  int o = blockIdx.x, t = threadIdx.x;
  __shared__ float buf[II];
  __shared__ float red[4];
  float mx = -1e30f;
  for (int i = t; i < II; i += 256) {
    float a = 0.f;
#pragma unroll
    for (int d = 0; d < 16; ++d) a += agreep[(size_t)(o * 16 + d) * II + i];
    float val = b_ij[i * OO + o] + a * (1.0f / (float)BB);
    b_ij[i * OO + o] = val;
    buf[i] = val;
    mx = fmaxf(mx, val);
  }
  for (int off = 32; off; off >>= 1) mx = fmaxf(mx, __shfl_down(mx, off));
  if ((t & 63) == 0) red[t >> 6] = mx;
  __syncthreads();
  mx = fmaxf(fmaxf(red[0], red[1]), fmaxf(red[2], red[3]));
  __syncthreads();
  float sum = 0.f;
  for (int i = t; i < II; i += 256) {
    float e = expf(buf[i] - mx);
    buf[i] = e;
    sum += e;
  }
  for (int off = 32; off; off >>= 1) sum += __shfl_down(sum, off);
  if ((t & 63) == 0) red[t >> 6] = sum;
  __syncthreads();
  sum = red[0] + red[1] + red[2] + red[3];
  float inv = 1.0f / sum;
  for (int i = t; i < II; i += 256) c[i * OO + o] = buf[i] * inv;
}

// ---------------- s partials: spart[ch][b][od] ----------------
// block (bt, ch): 32 b x 160 od x 16 i. thread: 4 b x 5 od.
__global__ __launch_bounds__(256) void k_s_part(const float* __restrict__ xT,
                                                const float* __restrict__ W,
                                                const float* __restrict__ c,
                                                float* __restrict__ spart) {
  __shared__ float smem[5248];      // wc: 4*1280=5120; epilogue: 32*164=5248
  int bt = blockIdx.x;              // 0..15
  int ch = blockIdx.y;              // 0..71
  int b0 = bt * BT;
  int i0 = ch * IC;
  int t = threadIdx.x;
  int bq = t & 7;    // b = b0 + bq*4 + bb
  int og = t >> 3;   // od = og*5 + r, og in [0,32)
  float acc[4][5];
#pragma unroll
  for (int bb = 0; bb < 4; ++bb)
#pragma unroll
    for (int r = 0; r < 5; ++r) acc[bb][r] = 0.f;

  for (int g = 0; g < 4; ++g) {
    int ig = i0 + g * 4;
    __syncthreads();
    // stage wc = c (.) W for 4 i's: 1280 float4
#pragma unroll
    for (int q = 0; q < 5; ++q) {
      int e4 = q * 256 + t;         // float4 index in [0,1280)
      int ii = e4 / 320;
      int rem = e4 - ii * 320;
      int o = rem >> 5;             // 32 float4 per o
      float cv = c[(ig + ii) * OO + o];
      float4 w4 = *(const float4*)&W[(size_t)(ig + ii) * 1280 + rem * 4];
      float4 r4;
      r4.x = w4.x * cv; r4.y = w4.y * cv; r4.z = w4.z * cv; r4.w = w4.w * cv;
      *(float4*)&smem[ii * 1280 + rem * 4] = r4;
    }
    __syncthreads();
#pragma unroll
    for (int ii = 0; ii < 4; ++ii) {
      int i = ig + ii;
      float xr[8][4];
#pragma unroll
      for (int j = 0; j < 8; ++j) {
        float4 q4 = *(const float4*)&xT[(size_t)(i * 8 + j) * BB + b0 + bq * 4];
        xr[j][0] = q4.x; xr[j][1] = q4.y; xr[j][2] = q4.z; xr[j][3] = q4.w;
      }
      const float* wrow = &smem[ii * 1280 + og * 40];   // 5 od * 8 j
#pragma unroll
      for (int r = 0; r < 5; ++r) {
        float4 w0 = *(const float4*)&wrow[r * 8];
        float4 w1 = *(const float4*)&wrow[r * 8 + 4];
#pragma unroll
        for (int bb = 0; bb < 4; ++bb) {
          float a = acc[bb][r];
          a = fmaf(xr[0][bb], w0.x, a);
          a = fmaf(xr[1][bb], w0.y, a);
          a = fmaf(xr[2][bb], w0.z, a);
          a = fmaf(xr[3][bb], w0.w, a);
          a = fmaf(xr[4][bb], w1.x, a);
          a = fmaf(xr[5][bb], w1.y, a);
          a = fmaf(xr[6][bb], w1.z, a);
          a = fmaf(xr[7][bb], w1.w, a);
          acc[bb][r] = a;
        }
      }
    }
  }
  // epilogue: LDS transpose for coalesced float4 global stores
  __syncthreads();
#pragma unroll
  for (int bb = 0; bb < 4; ++bb)
#pragma unroll
    for (int r = 0; r < 5; ++r)
      smem[(bq * 4 + bb) * 164 + og * 5 + r] = acc[bb][r];
  __syncthreads();
  float* dst = &spart[(size_t)ch * BB * OD + (size_t)b0 * OD];
#pragma unroll
  for (int k2 = 0; k2 < 5; ++k2) {
    int idx = k2 * 256 + t;         // float4 index over 1280
    int row = idx / 40;
    int col4 = idx - row * 40;
    float4 val = *(const float4*)&smem[row * 164 + col4 * 4];
    *(float4*)&dst[row * 160 + col4 * 4] = val;
  }
}

// ---------------- reduce partials + squash ----------------
__global__ __launch_bounds__(256) void k_squash(const float* __restrict__ spart,
                                                float* __restrict__ v) {
  int t = blockIdx.x * 256 + threadIdx.x;  // over B*OD = 81920
  float s = 0.f;
#pragma unroll 8
  for (int ns = 0; ns < NS; ++ns) s += spart[(size_t)ns * (BB * OD) + t];
  float sq = s * s;
  sq += __shfl_xor(sq, 1);
  sq += __shfl_xor(sq, 2);
  sq += __shfl_xor(sq, 4);
  sq += __shfl_xor(sq, 8);
  float scale = sqrtf(sq) / (1.0f + sq);
  v[t] = s * scale;
}

// ---------------- G partials: Gp[bh][od][k] ----------------
// block (kt, bh): 32 k x 160 od, contraction over nch*16 b's. thread: 4 k x 5 od.
__global__ __launch_bounds__(256) void k_G(const float* __restrict__ xT,
                                           const float* __restrict__ v,
                                           float* __restrict__ Gp, int nch) {
  __shared__ float smem[16 * 160];  // v-stage: 10 KB
  int k0 = blockIdx.x * 32;         // 288 tiles
  int bh = blockIdx.y;
  int t = threadIdx.x;
  int kq = t & 7;                   // k = k0 + kq*4 + kk
  int og = t >> 3;                  // od = og*5 + r, og in [0,32)
  float acc[4][5];
#pragma unroll
  for (int kk = 0; kk < 4; ++kk)
#pragma unroll
    for (int r = 0; r < 5; ++r) acc[kk][r] = 0.f;
  int b0 = bh * (nch * 16);

  for (int c2 = 0; c2 < nch; ++c2) {
    int bc = b0 + c2 * 16;
    __syncthreads();
    // stage v[bc:bc+16][0:160] (640 float4)
    for (int idx = t; idx < 640; idx += 256) {
      int b = idx / 40;
      int q = idx - b * 40;
      *(float4*)&smem[b * 160 + q * 4] = *(const float4*)&v[(size_t)(bc + b) * 160 + q * 4];
    }
    __syncthreads();
    float xr[4][16];
#pragma unroll
    for (int kk = 0; kk < 4; ++kk) {
      size_t row = (size_t)(k0 + kq * 4 + kk) * BB + bc;
#pragma unroll
      for (int q = 0; q < 4; ++q) {
        float4 a4 = *(const float4*)&xT[row + q * 4];
        xr[kk][q * 4 + 0] = a4.x; xr[kk][q * 4 + 1] = a4.y;
        xr[kk][q * 4 + 2] = a4.z; xr[kk][q * 4 + 3] = a4.w;
      }
    }
#pragma unroll
    for (int b = 0; b < 16; ++b) {
      const float* vp = &smem[b * 160 + og * 5];
#pragma unroll
      for (int r = 0; r < 5; ++r) {
        float vv_ = vp[r];
        acc[0][r] = fmaf(xr[0][b], vv_, acc[0][r]);
        acc[1][r] = fmaf(xr[1][b], vv_, acc[1][r]);
        acc[2][r] = fmaf(xr[2][b], vv_, acc[2][r]);
        acc[3][r] = fmaf(xr[3][b], vv_, acc[3][r]);
      }
    }
  }
  // store: 4 consecutive k per (od) -> float4, coalesced across kq lanes
#pragma unroll
  for (int r = 0; r < 5; ++r) {
    int od = og * 5 + r;
    float4 st = {acc[0][r], acc[1][r], acc[2][r], acc[3][r]};
    *(float4*)&Gp[((size_t)bh * OD + od) * KK + k0 + kq * 4] = st;
  }
}

// ---------------- agreep[od][i] = sum_{j,bh} W[i,o,d,j] * Gp[bh][od][i*8+j] ----------------
__global__ __launch_bounds__(256) void k_WGred(const float* __restrict__ W,
                                               const float* __restrict__ Gp,
                                               float* __restrict__ agreep, int gbh) {
  int od = blockIdx.x;              // 160
  int o = od >> 4, d = od & 15;
  int t = threadIdx.x;
  for (int ic = 0; ic < 5; ++ic) {
    int i = ic * 256 + t;
    if (i >= II) break;
    float4 g0 = {0.f, 0.f, 0.f, 0.f}, g1 = {0.f, 0.f, 0.f, 0.f};
    for (int bh = 0; bh < gbh; ++bh) {
      const float* gp = &Gp[((size_t)bh * OD + od) * KK + (size_t)i * 8];
      float4 a0 = *(const float4*)gp;
      float4 a1 = *(const float4*)(gp + 4);
      g0.x += a0.x; g0.y += a0.y; g0.z += a0.z; g0.w += a0.w;
      g1.x += a1.x; g1.y += a1.y; g1.z += a1.z; g1.w += a1.w;
    }
    const float* wp = &W[(size_t)((i * OO + o) * DD + d) * JJ];
    float4 w0 = *(const float4*)wp;
    float4 w1 = *(const float4*)(wp + 4);
    float acc = w0.x * g0.x + w0.y * g0.y + w0.z * g0.z + w0.w * g0.w +
                w1.x * g1.x + w1.y * g1.y + w1.z * g1.z + w1.w * g1.w;
    agreep[(size_t)od * II + i] = acc;
  }
}

extern "C" void kernel_launch(void* const* d_in, const int* in_sizes, int n_in,
                              void* d_out, int out_size, void* d_ws, size_t ws_size,
                              hipStream_t stream) {
  const float* x = (const float*)d_in[0];   // [512][1152][8]
  const float* W = (const float*)d_in[1];   // [1152][10][16][8]
  float* out = (float*)d_out;               // [512][10][16][1] == flat v
  float* ws = (float*)d_ws;

  float* b_ij = ws;                 // 11520
  float* c    = ws + 11520;         // 11520
  float* vv   = ws + 23040;         // 81920
  float* xT   = ws + 104960;        // 9216*512 = 4718592
  float* sp   = ws + 4823552;       // 72*81920 = 5898240; end = 10721792

  size_t wsf = ws_size / 4;
  int gbh, nch;
  float *Gp, *agreep;
  if (wsf >= 10721792 + 184320) {
    gbh = 4; nch = 8;               // Gp = [4][160][9216] = 5898240, aliases sp
    Gp = sp;
    agreep = ws + 10721792;         // 160*1152 = 184320
  } else {
    gbh = 2; nch = 16;              // Gp = [2][160][9216] = 2949120, inside sp
    Gp = sp;
    agreep = sp + 2949120;          // + 184320 = 3133440 <= 5898240, fits proven ws
  }

  hipMemsetAsync(b_ij, 0, 11520 * sizeof(float), stream);
  k_transpose<<<dim3(288, 16), 256, 0, stream>>>(x, xT);
  k_fill<<<45, 256, 0, stream>>>(c);   // softmax of zeros = uniform

  for (int it = 0; it < 3; ++it) {
    k_s_part<<<dim3(NBT, NS), 256, 0, stream>>>(xT, W, c, sp);
    k_squash<<<320, 256, 0, stream>>>(sp, it == 2 ? out : vv);
    if (it < 2) {
      k_G<<<dim3(288, gbh), 256, 0, stream>>>(xT, vv, Gp, nch);
      k_WGred<<<160, 256, 0, stream>>>(W, Gp, agreep, gbh);
      k_bupd_softmax<<<OO, 256, 0, stream>>>(b_ij, agreep, c);
    }
  }
}

// Round 8
// 432.233 us; speedup vs baseline: 1.0613x; 1.0613x over previous
//
#include <hip/hip_runtime.h>

#define BB 512
#define II 1152
#define OO 10
#define DD 16
#define JJ 8
#define OD 160           // OO*DD
#define KK (II*JJ)       // 9216

// s_part config (R2 proven)
#define BT 64            // b-tile
#define NBT (BB/BT)      // 8
#define IC 16            // i-chunk
#define NS (II/IC)       // 72

// ---------------- transpose x[b][k] -> xT[k][b] ----------------
__global__ __launch_bounds__(256) void k_transpose(const float* __restrict__ x,
                                                   float* __restrict__ xT) {
  __shared__ float tile[32][33];
  int kb = blockIdx.x;            // 288 tiles of k
  int bb = blockIdx.y;            // 16 tiles of b
  int tx = threadIdx.x & 31, ty = threadIdx.x >> 5;  // 32 x 8
  int k0 = kb * 32, b0 = bb * 32;
#pragma unroll
  for (int r = ty; r < 32; r += 8)
    tile[r][tx] = x[(size_t)(b0 + r) * KK + k0 + tx];
  __syncthreads();
#pragma unroll
  for (int r = ty; r < 32; r += 8)
    xT[(size_t)(k0 + r) * BB + b0 + tx] = tile[tx][r];
}

// ---------------- fill c with uniform 1/1152 (softmax of zeros) ----------------
__global__ __launch_bounds__(256) void k_fill(float* __restrict__ c) {
  c[blockIdx.x * 256 + threadIdx.x] = 1.0f / 1152.0f;
}

// ---------------- b update (from agreep[od][i]) + softmax over i ----------------
__global__ __launch_bounds__(256) void k_bupd_softmax(float* __restrict__ b_ij,
                                                      const float* __restrict__ agreep,
                                                      float* __restrict__ c) {
  int o = blockIdx.x, t = threadIdx.x;
  __shared__ float buf[II];
  __shared__ float red[4];
  float mx = -1e30f;
  for (int i = t; i < II; i += 256) {
    float a = 0.f;
#pragma unroll
    for (int d = 0; d < 16; ++d) a += agreep[(size_t)(o * 16 + d) * II + i];
    float val = b_ij[i * OO + o] + a * (1.0f / (float)BB);
    b_ij[i * OO + o] = val;
    buf[i] = val;
    mx = fmaxf(mx, val);
  }
  for (int off = 32; off; off >>= 1) mx = fmaxf(mx, __shfl_down(mx, off));
  if ((t & 63) == 0) red[t >> 6] = mx;
  __syncthreads();
  mx = fmaxf(fmaxf(red[0], red[1]), fmaxf(red[2], red[3]));
  __syncthreads();
  float sum = 0.f;
  for (int i = t; i < II; i += 256) {
    float e = expf(buf[i] - mx);
    buf[i] = e;
    sum += e;
  }
  for (int off = 32; off; off >>= 1) sum += __shfl_down(sum, off);
  if ((t & 63) == 0) red[t >> 6] = sum;
  __syncthreads();
  sum = red[0] + red[1] + red[2] + red[3];
  float inv = 1.0f / sum;
  for (int i = t; i < II; i += 256) c[i * OO + o] = buf[i] * inv;
}

// ---------------- s partials: spart[ch][b][od] (R2 proven version) ----------------
// block (bt, ch): 64 b's x all 160 od x 16 i's. thread: 4 b x 10 od.
__global__ __launch_bounds__(256) void k_s_part(const float* __restrict__ xT,
                                                const float* __restrict__ W,
                                                const float* __restrict__ c,
                                                float* __restrict__ spart) {
  __shared__ float smem[64 * 164];  // wc uses first 5120; epilogue uses 64x164
  int bt = blockIdx.x;              // 0..7
  int ch = blockIdx.y;              // 0..71
  int b0 = bt * BT;
  int i0 = ch * IC;
  int t = threadIdx.x;
  int bq = t & 15;   // b = b0 + bq*4 + bb
  int og = t >> 4;   // od = og*10 + r
  float acc[4][10];
#pragma unroll
  for (int bb = 0; bb < 4; ++bb)
#pragma unroll
    for (int r = 0; r < 10; ++r) acc[bb][r] = 0.f;

  for (int g = 0; g < 4; ++g) {
    int ig = i0 + g * 4;
    __syncthreads();
    // stage wc = c (.) W for 4 i's: 4*1280 floats
#pragma unroll
    for (int q = 0; q < 5; ++q) {
      int e4 = q * 256 + t;         // float4 index in [0,1280)
      int ii = e4 / 320;
      int rem = e4 - ii * 320;
      int o = rem >> 5;             // 32 float4 per o
      float cv = c[(ig + ii) * OO + o];
      float4 w4 = *(const float4*)&W[(size_t)(ig + ii) * 1280 + rem * 4];
      float4 r4;
      r4.x = w4.x * cv; r4.y = w4.y * cv; r4.z = w4.z * cv; r4.w = w4.w * cv;
      *(float4*)&smem[ii * 1280 + rem * 4] = r4;
    }
    __syncthreads();
#pragma unroll
    for (int ii = 0; ii < 4; ++ii) {
      int i = ig + ii;
      float xr[8][4];
#pragma unroll
      for (int j = 0; j < 8; ++j) {
        float4 q4 = *(const float4*)&xT[(size_t)(i * 8 + j) * BB + b0 + bq * 4];
        xr[j][0] = q4.x; xr[j][1] = q4.y; xr[j][2] = q4.z; xr[j][3] = q4.w;
      }
      const float* wrow = &smem[ii * 1280 + og * 80];
#pragma unroll
      for (int r = 0; r < 10; ++r) {
        float4 w0 = *(const float4*)&wrow[r * 8];
        float4 w1 = *(const float4*)&wrow[r * 8 + 4];
#pragma unroll
        for (int bb = 0; bb < 4; ++bb) {
          float a = acc[bb][r];
          a = fmaf(xr[0][bb], w0.x, a);
          a = fmaf(xr[1][bb], w0.y, a);
          a = fmaf(xr[2][bb], w0.z, a);
          a = fmaf(xr[3][bb], w0.w, a);
          a = fmaf(xr[4][bb], w1.x, a);
          a = fmaf(xr[5][bb], w1.y, a);
          a = fmaf(xr[6][bb], w1.z, a);
          a = fmaf(xr[7][bb], w1.w, a);
          acc[bb][r] = a;
        }
      }
    }
  }
  // epilogue: LDS transpose for coalesced global stores
  __syncthreads();
#pragma unroll
  for (int bb = 0; bb < 4; ++bb)
#pragma unroll
    for (int r = 0; r < 10; ++r)
      smem[(bq * 4 + bb) * 164 + og * 10 + r] = acc[bb][r];
  __syncthreads();
  float* dst = &spart[(size_t)ch * BB * OD + (size_t)b0 * OD];
#pragma unroll
  for (int k2 = 0; k2 < 10; ++k2) {
    int idx = k2 * 256 + t;         // float4 index over 2560
    int row = idx / 40;
    int col4 = idx - row * 40;
    float4 val = *(const float4*)&smem[row * 164 + col4 * 4];
    *(float4*)&dst[row * 160 + col4 * 4] = val;
  }
}

// ---------------- reduce partials + squash (writes v and vT) ----------------
__global__ __launch_bounds__(256) void k_squash(const float* __restrict__ spart,
                                                float* __restrict__ v,
                                                float* __restrict__ vT) {
  int t = blockIdx.x * 256 + threadIdx.x;  // over B*OD = 81920
  float s = 0.f;
#pragma unroll 8
  for (int ns = 0; ns < NS; ++ns) s += spart[(size_t)ns * (BB * OD) + t];
  float sq = s * s;
  sq += __shfl_xor(sq, 1);
  sq += __shfl_xor(sq, 2);
  sq += __shfl_xor(sq, 4);
  sq += __shfl_xor(sq, 8);
  float scale = sqrtf(sq) / (1.0f + sq);
  float val = s * scale;
  v[t] = val;
  int b = t / 160, od = t - b * 160;
  vT[(size_t)od * BB + b] = val;   // transposed copy for k_G (scatter, tiny)
}

// ---------------- G partials, register-streaming, no LDS/barriers ----------------
// Gp[bh][od][k]. Block (kt, oh, bh): 64 k x 80 od, contraction over bchunk b's.
// Thread: kq = t&15 -> 4 consecutive k; oq = t>>4 -> 5 od. acc[4][5] scalars.
__global__ __launch_bounds__(256) void k_G(const float* __restrict__ xT,
                                           const float* __restrict__ vT,
                                           float* __restrict__ Gp, int bchunk) {
  int t = threadIdx.x;
  int kq = t & 15;                  // 16 groups x 4 k = 64 k
  int oq = t >> 4;                  // 16 groups x 5 od = 80 od
  int k0 = blockIdx.x * 64;         // 144 tiles
  int oh = blockIdx.y;              // 0..1 (od half)
  int bh = blockIdx.z;              // 0..gbh-1
  int b0 = bh * bchunk;
  int nsteps = bchunk >> 2;

  const float* xp = xT + (size_t)(k0 + kq * 4) * BB + b0;
  const float* vp = vT + (size_t)(oh * 80 + oq * 5) * BB + b0;

  float acc[4][5];
#pragma unroll
  for (int kk = 0; kk < 4; ++kk)
#pragma unroll
    for (int r = 0; r < 5; ++r) acc[kk][r] = 0.f;

#pragma unroll 2
  for (int bi = 0; bi < nsteps; ++bi) {
    float4 x4[4], v4[5];
#pragma unroll
    for (int kk = 0; kk < 4; ++kk)
      x4[kk] = *(const float4*)(xp + (size_t)kk * BB + bi * 4);
#pragma unroll
    for (int r = 0; r < 5; ++r)
      v4[r] = *(const float4*)(vp + (size_t)r * BB + bi * 4);
#pragma unroll
    for (int kk = 0; kk < 4; ++kk)
#pragma unroll
      for (int r = 0; r < 5; ++r) {
        float a = acc[kk][r];
        a = fmaf(x4[kk].x, v4[r].x, a);
        a = fmaf(x4[kk].y, v4[r].y, a);
        a = fmaf(x4[kk].z, v4[r].z, a);
        a = fmaf(x4[kk].w, v4[r].w, a);
        acc[kk][r] = a;
      }
  }

  // store: 4 consecutive k -> one float4 per od, coalesced across kq lanes
#pragma unroll
  for (int r = 0; r < 5; ++r) {
    int od = oh * 80 + oq * 5 + r;
    float4 st = {acc[0][r], acc[1][r], acc[2][r], acc[3][r]};
    *(float4*)&Gp[((size_t)bh * OD + od) * KK + k0 + kq * 4] = st;
  }
}

// ---------------- agreep[od][i] = sum_{j,bh} W[i,o,d,j] * Gp[bh][od][i*8+j] ----------------
__global__ __launch_bounds__(256) void k_WGred(const float* __restrict__ W,
                                               const float* __restrict__ Gp,
                                               float* __restrict__ agreep, int gbh) {
  int od = blockIdx.x;              // 160
  int o = od >> 4, d = od & 15;
  int t = threadIdx.x;
  for (int ic = 0; ic < 5; ++ic) {
    int i = ic * 256 + t;
    if (i >= II) break;
    float4 g0 = {0.f, 0.f, 0.f, 0.f}, g1 = {0.f, 0.f, 0.f, 0.f};
    for (int bh = 0; bh < gbh; ++bh) {
      const float* gp = &Gp[((size_t)bh * OD + od) * KK + (size_t)i * 8];
      float4 a0 = *(const float4*)gp;
      float4 a1 = *(const float4*)(gp + 4);
      g0.x += a0.x; g0.y += a0.y; g0.z += a0.z; g0.w += a0.w;
      g1.x += a1.x; g1.y += a1.y; g1.z += a1.z; g1.w += a1.w;
    }
    const float* wp = &W[(size_t)((i * OO + o) * DD + d) * JJ];
    float4 w0 = *(const float4*)wp;
    float4 w1 = *(const float4*)(wp + 4);
    float acc = w0.x * g0.x + w0.y * g0.y + w0.z * g0.z + w0.w * g0.w +
                w1.x * g1.x + w1.y * g1.y + w1.z * g1.z + w1.w * g1.w;
    agreep[(size_t)od * II + i] = acc;
  }
}

extern "C" void kernel_launch(void* const* d_in, const int* in_sizes, int n_in,
                              void* d_out, int out_size, void* d_ws, size_t ws_size,
                              hipStream_t stream) {
  const float* x = (const float*)d_in[0];   // [512][1152][8]
  const float* W = (const float*)d_in[1];   // [1152][10][16][8]
  float* out = (float*)d_out;               // [512][10][16][1] == flat v
  float* ws = (float*)d_ws;

  float* b_ij = ws;                 // 11520
  float* c    = ws + 11520;         // 11520
  float* vv   = ws + 23040;         // 81920
  float* vT   = ws + 104960;        // 81920
  float* xT   = ws + 186880;        // 9216*512 = 4718592
  float* sp   = ws + 4905472;       // 72*81920 = 5898240; end = 10803712

  size_t wsf = ws_size / 4;
  int gbh;
  float *Gp, *agreep;
  if (wsf >= 10803712 + 184320) {
    gbh = 4;                        // Gp = [4][160][9216] = 5898240, aliases sp exactly
    Gp = sp;
    agreep = ws + 10803712;         // 160*1152 = 184320
  } else {
    gbh = 2;                        // Gp = [2][160][9216] = 2949120, inside sp
    Gp = sp;
    agreep = sp + 2949120;          // + 184320 = 3133440 <= 5898240
  }
  int bchunk = BB / gbh;

  hipMemsetAsync(b_ij, 0, 11520 * sizeof(float), stream);
  k_transpose<<<dim3(288, 16), 256, 0, stream>>>(x, xT);
  k_fill<<<45, 256, 0, stream>>>(c);   // softmax of zeros = uniform

  for (int it = 0; it < 3; ++it) {
    k_s_part<<<dim3(NBT, NS), 256, 0, stream>>>(xT, W, c, sp);
    k_squash<<<320, 256, 0, stream>>>(sp, it == 2 ? out : vv, vT);
    if (it < 2) {
      k_G<<<dim3(144, 2, gbh), 256, 0, stream>>>(xT, vT, Gp, bchunk);
      k_WGred<<<160, 256, 0, stream>>>(W, Gp, agreep, gbh);
      k_bupd_softmax<<<OO, 256, 0, stream>>>(b_ij, agreep, c);
    }
  }
}

// Round 9
// 315.490 us; speedup vs baseline: 1.4540x; 1.3700x over previous
//
#include <hip/hip_runtime.h>

#define BB 512
#define II 1152
#define OO 10
#define DD 16
#define JJ 8
#define OD 160           // OO*DD
#define KK (II*JJ)       // 9216

// s_part config (R2 proven)
#define BT 64            // b-tile
#define NBT (BB/BT)      // 8
#define IC 16            // i-chunk
#define NS (II/IC)       // 72

// ---------------- transpose x[b][k] -> xT[k][b] ----------------
__global__ __launch_bounds__(256) void k_transpose(const float* __restrict__ x,
                                                   float* __restrict__ xT) {
  __shared__ float tile[32][33];
  int kb = blockIdx.x;            // 288 tiles of k
  int bb = blockIdx.y;            // 16 tiles of b
  int tx = threadIdx.x & 31, ty = threadIdx.x >> 5;  // 32 x 8
  int k0 = kb * 32, b0 = bb * 32;
#pragma unroll
  for (int r = ty; r < 32; r += 8)
    tile[r][tx] = x[(size_t)(b0 + r) * KK + k0 + tx];
  __syncthreads();
#pragma unroll
  for (int r = ty; r < 32; r += 8)
    xT[(size_t)(k0 + r) * BB + b0 + tx] = tile[tx][r];
}

// ---------------- fill c with uniform 1/1152 (softmax of zeros) ----------------
__global__ __launch_bounds__(256) void k_fill(float* __restrict__ c) {
  c[blockIdx.x * 256 + threadIdx.x] = 1.0f / 1152.0f;
}

// ---------------- b update (from agreep[od][i]) + softmax over i ----------------
__global__ __launch_bounds__(256) void k_bupd_softmax(float* __restrict__ b_ij,
                                                      const float* __restrict__ agreep,
                                                      float* __restrict__ c) {
  int o = blockIdx.x, t = threadIdx.x;
  __shared__ float buf[II];
  __shared__ float red[4];
  float mx = -1e30f;
  for (int i = t; i < II; i += 256) {
    float a = 0.f;
#pragma unroll
    for (int d = 0; d < 16; ++d) a += agreep[(size_t)(o * 16 + d) * II + i];
    float val = b_ij[i * OO + o] + a * (1.0f / (float)BB);
    b_ij[i * OO + o] = val;
    buf[i] = val;
    mx = fmaxf(mx, val);
  }
  for (int off = 32; off; off >>= 1) mx = fmaxf(mx, __shfl_down(mx, off));
  if ((t & 63) == 0) red[t >> 6] = mx;
  __syncthreads();
  mx = fmaxf(fmaxf(red[0], red[1]), fmaxf(red[2], red[3]));
  __syncthreads();
  float sum = 0.f;
  for (int i = t; i < II; i += 256) {
    float e = expf(buf[i] - mx);
    buf[i] = e;
    sum += e;
  }
  for (int off = 32; off; off >>= 1) sum += __shfl_down(sum, off);
  if ((t & 63) == 0) red[t >> 6] = sum;
  __syncthreads();
  sum = red[0] + red[1] + red[2] + red[3];
  float inv = 1.0f / sum;
  for (int i = t; i < II; i += 256) c[i * OO + o] = buf[i] * inv;
}

// ---------------- s partials: spart[ch][b][od] (R2 proven version) ----------------
__global__ __launch_bounds__(256) void k_s_part(const float* __restrict__ xT,
                                                const float* __restrict__ W,
                                                const float* __restrict__ c,
                                                float* __restrict__ spart) {
  __shared__ float smem[64 * 164];  // wc uses first 5120; epilogue uses 64x164
  int bt = blockIdx.x;              // 0..7
  int ch = blockIdx.y;              // 0..71
  int b0 = bt * BT;
  int i0 = ch * IC;
  int t = threadIdx.x;
  int bq = t & 15;   // b = b0 + bq*4 + bb
  int og = t >> 4;   // od = og*10 + r
  float acc[4][10];
#pragma unroll
  for (int bb = 0; bb < 4; ++bb)
#pragma unroll
    for (int r = 0; r < 10; ++r) acc[bb][r] = 0.f;

  for (int g = 0; g < 4; ++g) {
    int ig = i0 + g * 4;
    __syncthreads();
#pragma unroll
    for (int q = 0; q < 5; ++q) {
      int e4 = q * 256 + t;         // float4 index in [0,1280)
      int ii = e4 / 320;
      int rem = e4 - ii * 320;
      int o = rem >> 5;             // 32 float4 per o
      float cv = c[(ig + ii) * OO + o];
      float4 w4 = *(const float4*)&W[(size_t)(ig + ii) * 1280 + rem * 4];
      float4 r4;
      r4.x = w4.x * cv; r4.y = w4.y * cv; r4.z = w4.z * cv; r4.w = w4.w * cv;
      *(float4*)&smem[ii * 1280 + rem * 4] = r4;
    }
    __syncthreads();
#pragma unroll
    for (int ii = 0; ii < 4; ++ii) {
      int i = ig + ii;
      float xr[8][4];
#pragma unroll
      for (int j = 0; j < 8; ++j) {
        float4 q4 = *(const float4*)&xT[(size_t)(i * 8 + j) * BB + b0 + bq * 4];
        xr[j][0] = q4.x; xr[j][1] = q4.y; xr[j][2] = q4.z; xr[j][3] = q4.w;
      }
      const float* wrow = &smem[ii * 1280 + og * 80];
#pragma unroll
      for (int r = 0; r < 10; ++r) {
        float4 w0 = *(const float4*)&wrow[r * 8];
        float4 w1 = *(const float4*)&wrow[r * 8 + 4];
#pragma unroll
        for (int bb = 0; bb < 4; ++bb) {
          float a = acc[bb][r];
          a = fmaf(xr[0][bb], w0.x, a);
          a = fmaf(xr[1][bb], w0.y, a);
          a = fmaf(xr[2][bb], w0.z, a);
          a = fmaf(xr[3][bb], w0.w, a);
          a = fmaf(xr[4][bb], w1.x, a);
          a = fmaf(xr[5][bb], w1.y, a);
          a = fmaf(xr[6][bb], w1.z, a);
          a = fmaf(xr[7][bb], w1.w, a);
          acc[bb][r] = a;
        }
      }
    }
  }
  __syncthreads();
#pragma unroll
  for (int bb = 0; bb < 4; ++bb)
#pragma unroll
    for (int r = 0; r < 10; ++r)
      smem[(bq * 4 + bb) * 164 + og * 10 + r] = acc[bb][r];
  __syncthreads();
  float* dst = &spart[(size_t)ch * BB * OD + (size_t)b0 * OD];
#pragma unroll
  for (int k2 = 0; k2 < 10; ++k2) {
    int idx = k2 * 256 + t;         // float4 index over 2560
    int row = idx / 40;
    int col4 = idx - row * 40;
    float4 val = *(const float4*)&smem[row * 164 + col4 * 4];
    *(float4*)&dst[row * 160 + col4 * 4] = val;
  }
}

// ---------------- reduce partials + squash ----------------
__global__ __launch_bounds__(256) void k_squash(const float* __restrict__ spart,
                                                float* __restrict__ v) {
  int t = blockIdx.x * 256 + threadIdx.x;  // over B*OD = 81920
  float s = 0.f;
#pragma unroll 8
  for (int ns = 0; ns < NS; ++ns) s += spart[(size_t)ns * (BB * OD) + t];
  float sq = s * s;
  sq += __shfl_xor(sq, 1);
  sq += __shfl_xor(sq, 2);
  sq += __shfl_xor(sq, 4);
  sq += __shfl_xor(sq, 8);
  float scale = sqrtf(sq) / (1.0f + sq);
  v[t] = s * scale;
}

// ---------------- G partials: Gp[bh][od][k], s_part-style coalescing ----------------
// G[k][od] = sum_b x[b][k] * v[b][od]. Contracts over b using ORIGINAL x layout
// (k contiguous). Block (kt, bh): 32 k x 160 od x 256 b. Thread: bq=t&7 -> 4
// consecutive k (one float4 x load, 8 lanes = 128B contiguous); og=t>>3 -> 5 od.
// v staged in LDS in 32-b chunks (20KB, contiguous loads); 512 FMA per barrier pair.
__global__ __launch_bounds__(256) void k_G(const float* __restrict__ x,
                                           const float* __restrict__ v,
                                           float* __restrict__ Gp) {
  __shared__ float smem[32 * 160];  // 20 KB v-stage
  int t = threadIdx.x;
  int bq = t & 7;                   // k = k0 + bq*4 + kk
  int og = t >> 3;                  // od = og*5 + r, og in [0,32)
  int k0 = blockIdx.x * 32;         // 288 k-tiles
  int bh = blockIdx.y;              // 0..1
  int bbase = bh * 256;

  float acc[4][5];
#pragma unroll
  for (int kk = 0; kk < 4; ++kk)
#pragma unroll
    for (int r = 0; r < 5; ++r) acc[kk][r] = 0.f;

  for (int ph = 0; ph < 8; ++ph) {
    int bc = bbase + ph * 32;
    __syncthreads();
    // stage v[bc:bc+32][0:160] -> smem: 1280 float4, fully contiguous
#pragma unroll
    for (int p = 0; p < 5; ++p) {
      int idx = p * 256 + t;        // float4 index in [0,1280)
      *(float4*)&smem[idx * 4] = *(const float4*)&v[(size_t)bc * 160 + idx * 4];
    }
    __syncthreads();
#pragma unroll 4
    for (int bi = 0; bi < 32; ++bi) {
      float4 x4 = *(const float4*)&x[(size_t)(bc + bi) * KK + k0 + bq * 4];
      const float* vrow = &smem[bi * 160 + og * 5];
      float xv[4] = {x4.x, x4.y, x4.z, x4.w};
#pragma unroll
      for (int r = 0; r < 5; ++r) {
        float vv_ = vrow[r];
#pragma unroll
        for (int kk = 0; kk < 4; ++kk)
          acc[kk][r] = fmaf(xv[kk], vv_, acc[kk][r]);
      }
    }
  }
  // store: 4 consecutive k -> one float4 per od; lanes bq 0..7 = 128B contiguous
#pragma unroll
  for (int r = 0; r < 5; ++r) {
    int od = og * 5 + r;
    float4 st = {acc[0][r], acc[1][r], acc[2][r], acc[3][r]};
    *(float4*)&Gp[((size_t)bh * OD + od) * KK + k0 + bq * 4] = st;
  }
}

// ---------------- agreep[od][i] = sum_{j,bh} W[i,o,d,j] * Gp[bh][od][i*8+j] ----------------
__global__ __launch_bounds__(256) void k_WGred(const float* __restrict__ W,
                                               const float* __restrict__ Gp,
                                               float* __restrict__ agreep) {
  int od = blockIdx.x;              // 160
  int o = od >> 4, d = od & 15;
  int t = threadIdx.x;
  for (int ic = 0; ic < 5; ++ic) {
    int i = ic * 256 + t;
    if (i >= II) break;
    const float* gp0 = &Gp[(size_t)od * KK + (size_t)i * 8];
    const float* gp1 = gp0 + (size_t)OD * KK;
    float4 a0 = *(const float4*)gp0;
    float4 a1 = *(const float4*)(gp0 + 4);
    float4 b0 = *(const float4*)gp1;
    float4 b1 = *(const float4*)(gp1 + 4);
    float4 g0 = {a0.x + b0.x, a0.y + b0.y, a0.z + b0.z, a0.w + b0.w};
    float4 g1 = {a1.x + b1.x, a1.y + b1.y, a1.z + b1.z, a1.w + b1.w};
    const float* wp = &W[(size_t)((i * OO + o) * DD + d) * JJ];
    float4 w0 = *(const float4*)wp;
    float4 w1 = *(const float4*)(wp + 4);
    float acc = w0.x * g0.x + w0.y * g0.y + w0.z * g0.z + w0.w * g0.w +
                w1.x * g1.x + w1.y * g1.y + w1.z * g1.z + w1.w * g1.w;
    agreep[(size_t)od * II + i] = acc;
  }
}

extern "C" void kernel_launch(void* const* d_in, const int* in_sizes, int n_in,
                              void* d_out, int out_size, void* d_ws, size_t ws_size,
                              hipStream_t stream) {
  const float* x = (const float*)d_in[0];   // [512][1152][8]
  const float* W = (const float*)d_in[1];   // [1152][10][16][8]
  float* out = (float*)d_out;               // [512][10][16][1] == flat v
  float* ws = (float*)d_ws;

  float* b_ij = ws;                 // 11520
  float* c    = ws + 11520;         // 11520
  float* vv   = ws + 23040;         // 81920
  float* xT   = ws + 186880;        // 9216*512 = 4718592 (hole before it is spare)
  float* sp   = ws + 4905472;       // 72*81920 = 5898240; end = 10803712
  float* Gp   = sp;                 // [2][160][9216] = 2949120, aliases sp (dead after squash)
  float* agreep = sp + 2949120;     // + 184320 = 3133440 <= 5898240 (fits proven ws)

  hipMemsetAsync(b_ij, 0, 11520 * sizeof(float), stream);
  k_transpose<<<dim3(288, 16), 256, 0, stream>>>(x, xT);
  k_fill<<<45, 256, 0, stream>>>(c);   // softmax of zeros = uniform

  for (int it = 0; it < 3; ++it) {
    k_s_part<<<dim3(NBT, NS), 256, 0, stream>>>(xT, W, c, sp);
    k_squash<<<320, 256, 0, stream>>>(sp, it == 2 ? out : vv);
    if (it < 2) {
      k_G<<<dim3(288, 2), 256, 0, stream>>>(x, vv, Gp);
      k_WGred<<<160, 256, 0, stream>>>(W, Gp, agreep);
      k_bupd_softmax<<<OO, 256, 0, stream>>>(b_ij, agreep, c);
    }
  }
}